// Round 4
// baseline (5033.922 us; speedup 1.0000x reference)
//
#include <hip/hip_runtime.h>
#include <hip/hip_bf16.h>
#include <math.h>

// LocalUniFormerBlock: BN -> windowed MHSA -> +res -> LN -> MLP(gelu) -> +res
// B=4 C=128 T=16 H=56 W=56, windows 4x7x7 (N=196), NH=4 HD=32, HID=512
//
// Round-4: global I/O is FLOAT32 (per the reference's dtypes; the bf16-I/O
// assumption of rounds 0-3 is what produced deterministic NaN — fp32 buffers
// read as bf16 decode ~0.4% of elements as NaN). Internal ws intermediates
// (win/Q/K/V) and LDS staging remain bf16: quantization error of
// intermediates is ~1e-2 absolute vs the 0.108 threshold.

typedef __hip_bfloat16 bf16;

__device__ __forceinline__ float b2f(bf16 v) { return __bfloat162float(v); }
__device__ __forceinline__ bf16  f2b(float v) { return __float2bfloat16(v); }

// ---------------------------------------------------------------- K1: BN + window partition (batched)
__global__ __launch_bounds__(256) void k1_bn_window(
    const float* __restrict__ x, const float* __restrict__ gamma, const float* __restrict__ beta,
    const float* __restrict__ mean, const float* __restrict__ var, bf16* __restrict__ win, int bw0)
{
    __shared__ bf16 sXn[196][130];
    __shared__ float sAc[128], sBc[128];
    int gbw = bw0 + blockIdx.x;      // global window id
    int b   = gbw >> 8;
    int wid = gbw & 255;
    int t0 = (wid >> 6) * 4;
    int h0 = ((wid >> 3) & 7) * 7;
    int w0 = (wid & 7) * 7;
    int tid = threadIdx.x;
    if (tid < 128) {
        float a = gamma[tid] * rsqrtf(var[tid] + 1e-5f);
        sAc[tid] = a;
        sBc[tid] = beta[tid] - mean[tid] * a;
    }
    __syncthreads();
    for (int idx = tid; idx < 128 * 196; idx += 256) {
        int c = idx / 196;
        int n = idx - c * 196;
        int wt = n / 49; int rem = n - wt * 49;
        int wh = rem / 7; int ww = rem - wh * 7;
        int gi = (((b * 128 + c) * 16 + (t0 + wt)) * 56 + (h0 + wh)) * 56 + (w0 + ww);
        float v = x[gi];
        sXn[n][c] = f2b(v * sAc[c] + sBc[c]);
    }
    __syncthreads();
    bf16* dst = win + (long)blockIdx.x * (196 * 128);   // batch-local row
    for (int idx = tid; idx < 196 * 128; idx += 256) {
        int n = idx >> 7; int c = idx & 127;
        dst[idx] = sXn[n][c];
    }
}

// ---------------------------------------------------------------- K2: QKV GEMM (batch-local M, N=384, K=128)
__global__ __launch_bounds__(256) void k2_qkv(
    const bf16* __restrict__ win, const float* __restrict__ qkv_w, const float* __restrict__ qkv_b,
    bf16* __restrict__ Q, bf16* __restrict__ K, bf16* __restrict__ V)
{
    __shared__ bf16 sA[64][130];
    __shared__ bf16 sB[128][68];
    int t0 = blockIdx.x * 64;        // batch-local token
    int j0 = blockIdx.y * 64;
    int tid = threadIdx.x;
    for (int idx = tid; idx < 64 * 128; idx += 256) {
        int i = idx >> 7; int c = idx & 127;
        sA[i][c] = win[(long)(t0 + i) * 128 + c];
    }
    for (int idx = tid; idx < 128 * 64; idx += 256) {
        int c = idx >> 6; int j = idx & 63;
        sB[c][j] = f2b(qkv_w[c * 384 + j0 + j]);
    }
    __syncthreads();
    int tx = tid & 15, ty = tid >> 4;
    float acc[4][4] = {};
    for (int c = 0; c < 128; ++c) {
        float a0 = b2f(sA[ty * 4 + 0][c]);
        float a1 = b2f(sA[ty * 4 + 1][c]);
        float a2 = b2f(sA[ty * 4 + 2][c]);
        float a3 = b2f(sA[ty * 4 + 3][c]);
        float bb0 = b2f(sB[c][tx * 4 + 0]);
        float bb1 = b2f(sB[c][tx * 4 + 1]);
        float bb2 = b2f(sB[c][tx * 4 + 2]);
        float bb3 = b2f(sB[c][tx * 4 + 3]);
        acc[0][0] += a0 * bb0; acc[0][1] += a0 * bb1; acc[0][2] += a0 * bb2; acc[0][3] += a0 * bb3;
        acc[1][0] += a1 * bb0; acc[1][1] += a1 * bb1; acc[1][2] += a1 * bb2; acc[1][3] += a1 * bb3;
        acc[2][0] += a2 * bb0; acc[2][1] += a2 * bb1; acc[2][2] += a2 * bb2; acc[2][3] += a2 * bb3;
        acc[3][0] += a3 * bb0; acc[3][1] += a3 * bb1; acc[3][2] += a3 * bb2; acc[3][3] += a3 * bb3;
    }
    bf16* outw = (j0 < 128) ? Q : (j0 < 256 ? K : V);
    int jb = j0 & 127;
    for (int di = 0; di < 4; ++di) {
        int tk = t0 + ty * 4 + di;
        int lbw = tk / 196; int n = tk - lbw * 196;  // batch-local window
        for (int dj = 0; dj < 4; ++dj) {
            int j = tx * 4 + dj;
            int hd = jb + j;
            int h = hd >> 5; int d = hd & 31;
            float v = acc[di][dj] + qkv_b[j0 + j];
            outw[((long)(lbw * 4 + h) * 196 + n) * 32 + d] = f2b(v);
        }
    }
}

// ---------------------------------------------------------------- K3: attention per (batch-local window, head)
__global__ __launch_bounds__(256) void k3_attn(
    const bf16* __restrict__ Q, const bf16* __restrict__ K, const bf16* __restrict__ V,
    bf16* __restrict__ attn_out)
{
    __shared__ bf16 sQ[196][34], sK[196][34], sV[196][34];
    __shared__ float sP[4][200];
    int bh = blockIdx.x;             // batch-local bw*4 + h
    int bw = bh >> 2; int h = bh & 3;
    int tid = threadIdx.x;
    const bf16* qp = Q + (long)bh * 196 * 32;
    const bf16* kp = K + (long)bh * 196 * 32;
    const bf16* vp = V + (long)bh * 196 * 32;
    for (int idx = tid; idx < 196 * 32; idx += 256) {
        int n = idx >> 5; int d = idx & 31;
        sQ[n][d] = qp[idx]; sK[n][d] = kp[idx]; sV[n][d] = vp[idx];
    }
    __syncthreads();
    int wv = tid >> 6; int lane = tid & 63;
    const float scale = 0.17677669529663687f;
    for (int i = wv; i < 196; i += 4) {
        float qr[32];
        #pragma unroll
        for (int d = 0; d < 32; ++d) qr[d] = b2f(sQ[i][d]);
        float s[4];
        float m = -1e30f;
        #pragma unroll
        for (int cc = 0; cc < 4; ++cc) {
            s[cc] = -1e30f;
            int jj = lane + 64 * cc;
            if (jj < 196) {
                float a = 0.f;
                #pragma unroll
                for (int d = 0; d < 32; ++d) a += qr[d] * b2f(sK[jj][d]);
                s[cc] = a * scale;
                m = fmaxf(m, s[cc]);
            }
        }
        #pragma unroll
        for (int off = 1; off < 64; off <<= 1) m = fmaxf(m, __shfl_xor(m, off, 64));
        float l = 0.f;
        #pragma unroll
        for (int cc = 0; cc < 4; ++cc) {
            int jj = lane + 64 * cc;
            if (jj < 196) {
                float p = expf(s[cc] - m);
                l += p;
                sP[wv][jj] = p;
            }
        }
        #pragma unroll
        for (int off = 1; off < 64; off <<= 1) l += __shfl_xor(l, off, 64);
        float inv = 1.0f / l;
        int d = lane & 31; int half = lane >> 5;
        float a = 0.f;
        for (int j = half; j < 196; j += 2) a += sP[wv][j] * b2f(sV[j][d]);
        a += __shfl_xor(a, 32, 64);
        if (half == 0)
            attn_out[((long)(bw * 196) + i) * 128 + h * 32 + d] = f2b(a * inv);
    }
}

// ---------------------------------------------------------------- K4: proj GEMM + residual -> d_out (ch-major, fp32)
__global__ __launch_bounds__(256) void k4_proj(
    const bf16* __restrict__ attn, const float* __restrict__ proj_w, const float* __restrict__ proj_b,
    const float* __restrict__ x, float* __restrict__ y, int bw0)
{
    __shared__ bf16 sA[64][130];
    __shared__ bf16 sB[128][68];
    int t0 = blockIdx.x * 64;        // batch-local token
    int j0 = blockIdx.y * 64;
    int tid = threadIdx.x;
    for (int idx = tid; idx < 64 * 128; idx += 256) {
        int i = idx >> 7; int c = idx & 127;
        sA[i][c] = attn[(long)(t0 + i) * 128 + c];
    }
    for (int idx = tid; idx < 128 * 64; idx += 256) {
        int c = idx >> 6; int j = idx & 63;
        sB[c][j] = f2b(proj_w[c * 128 + j0 + j]);
    }
    __syncthreads();
    int tx = tid & 15, ty = tid >> 4;
    float acc[4][4] = {};
    for (int c = 0; c < 128; ++c) {
        float a0 = b2f(sA[ty * 4 + 0][c]);
        float a1 = b2f(sA[ty * 4 + 1][c]);
        float a2 = b2f(sA[ty * 4 + 2][c]);
        float a3 = b2f(sA[ty * 4 + 3][c]);
        float bb0 = b2f(sB[c][tx * 4 + 0]);
        float bb1 = b2f(sB[c][tx * 4 + 1]);
        float bb2 = b2f(sB[c][tx * 4 + 2]);
        float bb3 = b2f(sB[c][tx * 4 + 3]);
        acc[0][0] += a0 * bb0; acc[0][1] += a0 * bb1; acc[0][2] += a0 * bb2; acc[0][3] += a0 * bb3;
        acc[1][0] += a1 * bb0; acc[1][1] += a1 * bb1; acc[1][2] += a1 * bb2; acc[1][3] += a1 * bb3;
        acc[2][0] += a2 * bb0; acc[2][1] += a2 * bb1; acc[2][2] += a2 * bb2; acc[2][3] += a2 * bb3;
        acc[3][0] += a3 * bb0; acc[3][1] += a3 * bb1; acc[3][2] += a3 * bb2; acc[3][3] += a3 * bb3;
    }
    for (int di = 0; di < 4; ++di) {
        int tk = t0 + ty * 4 + di;
        int gbw = bw0 + tk / 196;    // global window id
        int n = tk - (tk / 196) * 196;
        int b = gbw >> 8; int wid = gbw & 255;
        int wt = n / 49; int rem = n - wt * 49;
        int t = (wid >> 6) * 4 + wt;
        int hh = ((wid >> 3) & 7) * 7 + rem / 7;
        int wcol = (wid & 7) * 7 + (rem - (rem / 7) * 7);
        int thw = (t * 56 + hh) * 56 + wcol;
        for (int dj = 0; dj < 4; ++dj) {
            int j = j0 + tx * 4 + dj;
            float v = acc[di][dj] + proj_b[j] + x[(long)(b * 128 + j) * 50176 + thw];
            y[(long)(b * 128 + j) * 50176 + thw] = v;    // channel-major fp32, same layout as out
        }
    }
}

// ---------------------------------------------------------------- K5: LN + MLP + residual, IN-PLACE on d_out (fp32)
__global__ __launch_bounds__(256) void k5_mlp(
    float* __restrict__ y,           // in: x+attn residual (ch-major); out: final (ch-major)
    const float* __restrict__ ln_g, const float* __restrict__ ln_b,
    const float* __restrict__ w1, const float* __restrict__ b1,
    const float* __restrict__ w2, const float* __restrict__ b2)
{
    __shared__ bf16 sRes[64][130];
    __shared__ bf16 sLN[64][130];
    __shared__ bf16 sW1[128][34];
    __shared__ bf16 sW2[32][130];
    __shared__ bf16 sH[64][34];
    __shared__ float sMu[64], sRstd[64];
    __shared__ float sG[128], sBt[128];
    int tid = threadIdx.x;
    int g0 = blockIdx.x * 64;        // global token base; 50176%64==0 so one b per block
    int b = g0 / 50176;
    int thw0 = g0 - b * 50176;
    if (tid < 128) { sG[tid] = ln_g[tid]; sBt[tid] = ln_b[tid]; }
    // load 64 tokens x 128 ch from channel-major y (coalesced 64-token runs)
    for (int idx = tid; idx < 64 * 128; idx += 256) {
        int c = idx >> 6; int tok = idx & 63;
        sRes[tok][c] = f2b(y[(long)(b * 128 + c) * 50176 + thw0 + tok]);
    }
    __syncthreads();
    if (tid < 64) {
        float s = 0.f, s2 = 0.f;
        for (int c = 0; c < 128; ++c) { float v = b2f(sRes[tid][c]); s += v; s2 += v * v; }
        float mu = s * (1.0f / 128.0f);
        float var = s2 * (1.0f / 128.0f) - mu * mu;
        sMu[tid] = mu; sRstd[tid] = rsqrtf(fmaxf(var, 0.f) + 1e-5f);
    }
    __syncthreads();
    for (int idx = tid; idx < 64 * 128; idx += 256) {
        int tok = idx >> 7; int c = idx & 127;
        float v = (b2f(sRes[tok][c]) - sMu[tok]) * sRstd[tok] * sG[c] + sBt[c];
        sLN[tok][c] = f2b(v);
    }
    float acc[32];
    #pragma unroll
    for (int k = 0; k < 32; ++k) acc[k] = 0.f;
    int cc = tid & 127;      // fc2 output column
    int tok2 = tid >> 7;
    int hh = tid & 31;       // fc1 hidden column within chunk
    int tg = tid >> 5;
    for (int ch = 0; ch < 16; ++ch) {
        __syncthreads();
        for (int idx = tid; idx < 128 * 32; idx += 256) {
            int c = idx >> 5; int j = idx & 31;
            sW1[c][j] = f2b(w1[c * 512 + ch * 32 + j]);
        }
        for (int idx = tid; idx < 32 * 128; idx += 256) {
            int j = idx >> 7; int c = idx & 127;
            sW2[j][c] = f2b(w2[(ch * 32 + j) * 128 + c]);
        }
        __syncthreads();
        float b1v = b1[ch * 32 + hh];
        for (int k = 0; k < 8; ++k) {
            int tok = tg + 8 * k;
            float v = b1v;
            for (int c = 0; c < 128; ++c) v += b2f(sLN[tok][c]) * b2f(sW1[c][hh]);
            v = 0.5f * v * (1.0f + erff(v * 0.70710678118f));
            sH[tok][hh] = f2b(v);
        }
        __syncthreads();   // sH producers (waves by tg) -> consumers (waves by tok2)
        for (int k = 0; k < 32; ++k) {
            int tok = tok2 + 2 * k;
            float a = acc[k];
            for (int j = 0; j < 32; ++j) a += b2f(sH[tok][j]) * b2f(sW2[j][cc]);
            acc[k] = a;
        }
    }
    __syncthreads();
    // final: residual add in fp32 registers, stage fp32->LDS via two bf16? No:
    // stage via sLN (bf16) for coalesced transpose; quantization ~1e-2 << 0.108.
    float b2v = b2[cc];
    for (int k = 0; k < 32; ++k) {
        int tok = tok2 + 2 * k;
        float v = acc[k] + b2v + b2f(sRes[tok][cc]);
        sLN[tok][cc] = f2b(v);       // reuse sLN as output tile
    }
    __syncthreads();
    // write back in-place (same element set this block loaded)
    for (int idx = tid; idx < 128 * 64; idx += 256) {
        int c = idx >> 6; int tok = idx & 63;
        y[(long)(b * 128 + c) * 50176 + thw0 + tok] = b2f(sLN[tok][c]);
    }
}

// ----------------------------------------------------------------
extern "C" void kernel_launch(void* const* d_in, const int* in_sizes, int n_in,
                              void* d_out, int out_size, void* d_ws, size_t ws_size,
                              hipStream_t stream) {
    const float* x      = (const float*)d_in[0];
    const float* bn_g   = (const float*)d_in[1];
    const float* bn_b   = (const float*)d_in[2];
    const float* bn_m   = (const float*)d_in[3];
    const float* bn_v   = (const float*)d_in[4];
    const float* qkv_w  = (const float*)d_in[5];
    const float* qkv_b  = (const float*)d_in[6];
    const float* proj_w = (const float*)d_in[7];
    const float* proj_b = (const float*)d_in[8];
    const float* ln_g   = (const float*)d_in[9];
    const float* ln_b   = (const float*)d_in[10];
    const float* fc1_w  = (const float*)d_in[11];
    const float* fc1_b  = (const float*)d_in[12];
    const float* fc2_w  = (const float*)d_in[13];
    const float* fc2_b  = (const float*)d_in[14];
    float* out = (float*)d_out;

    // pick batch count so per-batch ws footprint (4 bf16 buffers) fits ws_size
    int NB = 1;
    while (NB < 64 && (size_t)205520896ull / NB > ws_size) NB *= 2;
    int WPB = 1024 / NB;             // windows per batch (>=16 so TPB%64==0)
    int TPB = WPB * 196;             // tokens per batch
    size_t seg = (size_t)TPB * 128 * 2;  // bytes per bf16 buffer

    char* ws = (char*)d_ws;
    bf16* win = (bf16*)(ws);             // reused as attn_out
    bf16* Qb  = (bf16*)(ws + seg);
    bf16* Kb  = (bf16*)(ws + 2 * seg);
    bf16* Vb  = (bf16*)(ws + 3 * seg);

    for (int bi = 0; bi < NB; ++bi) {
        int bw0 = bi * WPB;
        k1_bn_window<<<dim3(WPB), dim3(256), 0, stream>>>(x, bn_g, bn_b, bn_m, bn_v, win, bw0);
        k2_qkv<<<dim3(TPB / 64, 6), dim3(256), 0, stream>>>(win, qkv_w, qkv_b, Qb, Kb, Vb);
        k3_attn<<<dim3(WPB * 4), dim3(256), 0, stream>>>(Qb, Kb, Vb, win);
        k4_proj<<<dim3(TPB / 64, 2), dim3(256), 0, stream>>>(win, proj_w, proj_b, x, out, bw0);
    }
    k5_mlp<<<dim3(3136), dim3(256), 0, stream>>>(out, ln_g, ln_b, fc1_w, fc1_b, fc2_w, fc2_b);
}

// Round 5
// 3184.941 us; speedup vs baseline: 1.5805x; 1.5805x over previous
//
#include <hip/hip_runtime.h>
#include <hip/hip_bf16.h>
#include <math.h>

// LocalUniFormerBlock: BN -> windowed MHSA -> +res -> LN -> MLP(gelu) -> +res
// B=4 C=128 T=16 H=56 W=56, windows 4x7x7 (N=196), NH=4 HD=32, HID=512
//
// Round-5: k5 MLP converted to MFMA (16x16x32 bf16). Fragment layouts per the
// gfx950-verified mapping: A[m=lane&15][k=quad*8+j], B[n=lane&15][k=quad*8+j]
// (B stored transposed in LDS), C/D: row=quad*4+reg, col=lane&15.
// k1-k4 byte-identical to the round-4 passing version.

typedef __hip_bfloat16 bf16;
typedef __attribute__((ext_vector_type(8))) short short8;
typedef __attribute__((ext_vector_type(4))) float f32x4;

__device__ __forceinline__ float b2f(bf16 v) { return __bfloat162float(v); }
__device__ __forceinline__ bf16  f2b(float v) { return __float2bfloat16(v); }

// ---------------------------------------------------------------- K1: BN + window partition (batched)
__global__ __launch_bounds__(256) void k1_bn_window(
    const float* __restrict__ x, const float* __restrict__ gamma, const float* __restrict__ beta,
    const float* __restrict__ mean, const float* __restrict__ var, bf16* __restrict__ win, int bw0)
{
    __shared__ bf16 sXn[196][130];
    __shared__ float sAc[128], sBc[128];
    int gbw = bw0 + blockIdx.x;      // global window id
    int b   = gbw >> 8;
    int wid = gbw & 255;
    int t0 = (wid >> 6) * 4;
    int h0 = ((wid >> 3) & 7) * 7;
    int w0 = (wid & 7) * 7;
    int tid = threadIdx.x;
    if (tid < 128) {
        float a = gamma[tid] * rsqrtf(var[tid] + 1e-5f);
        sAc[tid] = a;
        sBc[tid] = beta[tid] - mean[tid] * a;
    }
    __syncthreads();
    for (int idx = tid; idx < 128 * 196; idx += 256) {
        int c = idx / 196;
        int n = idx - c * 196;
        int wt = n / 49; int rem = n - wt * 49;
        int wh = rem / 7; int ww = rem - wh * 7;
        int gi = (((b * 128 + c) * 16 + (t0 + wt)) * 56 + (h0 + wh)) * 56 + (w0 + ww);
        float v = x[gi];
        sXn[n][c] = f2b(v * sAc[c] + sBc[c]);
    }
    __syncthreads();
    bf16* dst = win + (long)blockIdx.x * (196 * 128);   // batch-local row
    for (int idx = tid; idx < 196 * 128; idx += 256) {
        int n = idx >> 7; int c = idx & 127;
        dst[idx] = sXn[n][c];
    }
}

// ---------------------------------------------------------------- K2: QKV GEMM (batch-local M, N=384, K=128)
__global__ __launch_bounds__(256) void k2_qkv(
    const bf16* __restrict__ win, const float* __restrict__ qkv_w, const float* __restrict__ qkv_b,
    bf16* __restrict__ Q, bf16* __restrict__ K, bf16* __restrict__ V)
{
    __shared__ bf16 sA[64][130];
    __shared__ bf16 sB[128][68];
    int t0 = blockIdx.x * 64;        // batch-local token
    int j0 = blockIdx.y * 64;
    int tid = threadIdx.x;
    for (int idx = tid; idx < 64 * 128; idx += 256) {
        int i = idx >> 7; int c = idx & 127;
        sA[i][c] = win[(long)(t0 + i) * 128 + c];
    }
    for (int idx = tid; idx < 128 * 64; idx += 256) {
        int c = idx >> 6; int j = idx & 63;
        sB[c][j] = f2b(qkv_w[c * 384 + j0 + j]);
    }
    __syncthreads();
    int tx = tid & 15, ty = tid >> 4;
    float acc[4][4] = {};
    for (int c = 0; c < 128; ++c) {
        float a0 = b2f(sA[ty * 4 + 0][c]);
        float a1 = b2f(sA[ty * 4 + 1][c]);
        float a2 = b2f(sA[ty * 4 + 2][c]);
        float a3 = b2f(sA[ty * 4 + 3][c]);
        float bb0 = b2f(sB[c][tx * 4 + 0]);
        float bb1 = b2f(sB[c][tx * 4 + 1]);
        float bb2 = b2f(sB[c][tx * 4 + 2]);
        float bb3 = b2f(sB[c][tx * 4 + 3]);
        acc[0][0] += a0 * bb0; acc[0][1] += a0 * bb1; acc[0][2] += a0 * bb2; acc[0][3] += a0 * bb3;
        acc[1][0] += a1 * bb0; acc[1][1] += a1 * bb1; acc[1][2] += a1 * bb2; acc[1][3] += a1 * bb3;
        acc[2][0] += a2 * bb0; acc[2][1] += a2 * bb1; acc[2][2] += a2 * bb2; acc[2][3] += a2 * bb3;
        acc[3][0] += a3 * bb0; acc[3][1] += a3 * bb1; acc[3][2] += a3 * bb2; acc[3][3] += a3 * bb3;
    }
    bf16* outw = (j0 < 128) ? Q : (j0 < 256 ? K : V);
    int jb = j0 & 127;
    for (int di = 0; di < 4; ++di) {
        int tk = t0 + ty * 4 + di;
        int lbw = tk / 196; int n = tk - lbw * 196;  // batch-local window
        for (int dj = 0; dj < 4; ++dj) {
            int j = tx * 4 + dj;
            int hd = jb + j;
            int h = hd >> 5; int d = hd & 31;
            float v = acc[di][dj] + qkv_b[j0 + j];
            outw[((long)(lbw * 4 + h) * 196 + n) * 32 + d] = f2b(v);
        }
    }
}

// ---------------------------------------------------------------- K3: attention per (batch-local window, head)
__global__ __launch_bounds__(256) void k3_attn(
    const bf16* __restrict__ Q, const bf16* __restrict__ K, const bf16* __restrict__ V,
    bf16* __restrict__ attn_out)
{
    __shared__ bf16 sQ[196][34], sK[196][34], sV[196][34];
    __shared__ float sP[4][200];
    int bh = blockIdx.x;             // batch-local bw*4 + h
    int bw = bh >> 2; int h = bh & 3;
    int tid = threadIdx.x;
    const bf16* qp = Q + (long)bh * 196 * 32;
    const bf16* kp = K + (long)bh * 196 * 32;
    const bf16* vp = V + (long)bh * 196 * 32;
    for (int idx = tid; idx < 196 * 32; idx += 256) {
        int n = idx >> 5; int d = idx & 31;
        sQ[n][d] = qp[idx]; sK[n][d] = kp[idx]; sV[n][d] = vp[idx];
    }
    __syncthreads();
    int wv = tid >> 6; int lane = tid & 63;
    const float scale = 0.17677669529663687f;
    for (int i = wv; i < 196; i += 4) {
        float qr[32];
        #pragma unroll
        for (int d = 0; d < 32; ++d) qr[d] = b2f(sQ[i][d]);
        float s[4];
        float m = -1e30f;
        #pragma unroll
        for (int cc = 0; cc < 4; ++cc) {
            s[cc] = -1e30f;
            int jj = lane + 64 * cc;
            if (jj < 196) {
                float a = 0.f;
                #pragma unroll
                for (int d = 0; d < 32; ++d) a += qr[d] * b2f(sK[jj][d]);
                s[cc] = a * scale;
                m = fmaxf(m, s[cc]);
            }
        }
        #pragma unroll
        for (int off = 1; off < 64; off <<= 1) m = fmaxf(m, __shfl_xor(m, off, 64));
        float l = 0.f;
        #pragma unroll
        for (int cc = 0; cc < 4; ++cc) {
            int jj = lane + 64 * cc;
            if (jj < 196) {
                float p = expf(s[cc] - m);
                l += p;
                sP[wv][jj] = p;
            }
        }
        #pragma unroll
        for (int off = 1; off < 64; off <<= 1) l += __shfl_xor(l, off, 64);
        float inv = 1.0f / l;
        int d = lane & 31; int half = lane >> 5;
        float a = 0.f;
        for (int j = half; j < 196; j += 2) a += sP[wv][j] * b2f(sV[j][d]);
        a += __shfl_xor(a, 32, 64);
        if (half == 0)
            attn_out[((long)(bw * 196) + i) * 128 + h * 32 + d] = f2b(a * inv);
    }
}

// ---------------------------------------------------------------- K4: proj GEMM + residual -> d_out (ch-major, fp32)
__global__ __launch_bounds__(256) void k4_proj(
    const bf16* __restrict__ attn, const float* __restrict__ proj_w, const float* __restrict__ proj_b,
    const float* __restrict__ x, float* __restrict__ y, int bw0)
{
    __shared__ bf16 sA[64][130];
    __shared__ bf16 sB[128][68];
    int t0 = blockIdx.x * 64;        // batch-local token
    int j0 = blockIdx.y * 64;
    int tid = threadIdx.x;
    for (int idx = tid; idx < 64 * 128; idx += 256) {
        int i = idx >> 7; int c = idx & 127;
        sA[i][c] = attn[(long)(t0 + i) * 128 + c];
    }
    for (int idx = tid; idx < 128 * 64; idx += 256) {
        int c = idx >> 6; int j = idx & 63;
        sB[c][j] = f2b(proj_w[c * 128 + j0 + j]);
    }
    __syncthreads();
    int tx = tid & 15, ty = tid >> 4;
    float acc[4][4] = {};
    for (int c = 0; c < 128; ++c) {
        float a0 = b2f(sA[ty * 4 + 0][c]);
        float a1 = b2f(sA[ty * 4 + 1][c]);
        float a2 = b2f(sA[ty * 4 + 2][c]);
        float a3 = b2f(sA[ty * 4 + 3][c]);
        float bb0 = b2f(sB[c][tx * 4 + 0]);
        float bb1 = b2f(sB[c][tx * 4 + 1]);
        float bb2 = b2f(sB[c][tx * 4 + 2]);
        float bb3 = b2f(sB[c][tx * 4 + 3]);
        acc[0][0] += a0 * bb0; acc[0][1] += a0 * bb1; acc[0][2] += a0 * bb2; acc[0][3] += a0 * bb3;
        acc[1][0] += a1 * bb0; acc[1][1] += a1 * bb1; acc[1][2] += a1 * bb2; acc[1][3] += a1 * bb3;
        acc[2][0] += a2 * bb0; acc[2][1] += a2 * bb1; acc[2][2] += a2 * bb2; acc[2][3] += a2 * bb3;
        acc[3][0] += a3 * bb0; acc[3][1] += a3 * bb1; acc[3][2] += a3 * bb2; acc[3][3] += a3 * bb3;
    }
    for (int di = 0; di < 4; ++di) {
        int tk = t0 + ty * 4 + di;
        int gbw = bw0 + tk / 196;    // global window id
        int n = tk - (tk / 196) * 196;
        int b = gbw >> 8; int wid = gbw & 255;
        int wt = n / 49; int rem = n - wt * 49;
        int t = (wid >> 6) * 4 + wt;
        int hh = ((wid >> 3) & 7) * 7 + rem / 7;
        int wcol = (wid & 7) * 7 + (rem - (rem / 7) * 7);
        int thw = (t * 56 + hh) * 56 + wcol;
        for (int dj = 0; dj < 4; ++dj) {
            int j = j0 + tx * 4 + dj;
            float v = acc[di][dj] + proj_b[j] + x[(long)(b * 128 + j) * 50176 + thw];
            y[(long)(b * 128 + j) * 50176 + thw] = v;    // channel-major fp32, same layout as out
        }
    }
}

// ---------------------------------------------------------------- K5: LN + MLP (MFMA) + residual, IN-PLACE on d_out
// Per block: 64 tokens. Hidden processed in 16 chunks of 32.
// fc1: per wave, M-tile = 16 tokens, 2 N-tiles x 4 K-steps = 8 MFMA/chunk.
// fc2: 8 N-tiles (128 ch) x 1 K-step = 8 MFMA/chunk, acc across chunks.
__global__ __launch_bounds__(256) void k5_mlp(
    float* __restrict__ y,           // in: x+attn residual (ch-major); out: final (ch-major)
    const float* __restrict__ ln_g, const float* __restrict__ ln_b,
    const float* __restrict__ w1, const float* __restrict__ b1,
    const float* __restrict__ w2, const float* __restrict__ b2)
{
    __shared__ __align__(16) bf16 sLN[64][136];   // LN activations; reused as out-stage
    __shared__ __align__(16) bf16 sW1t[32][136];  // W1 chunk, [hidden j][c]
    __shared__ __align__(16) bf16 sH[64][40];     // gelu(fc1) chunk, [tok][j]
    __shared__ __align__(16) bf16 sW2t[128][40];  // W2 chunk, [c][hidden j]
    __shared__ bf16 sRes[64][129];
    __shared__ float sMu[64], sRstd[64];
    __shared__ float sG[128], sBt[128];
    int tid = threadIdx.x;
    int g0 = blockIdx.x * 64;        // 50176%64==0 so one b per block
    int b = g0 / 50176;
    int thw0 = g0 - b * 50176;
    if (tid < 128) { sG[tid] = ln_g[tid]; sBt[tid] = ln_b[tid]; }
    for (int idx = tid; idx < 64 * 128; idx += 256) {
        int c = idx >> 6; int tok = idx & 63;
        sRes[tok][c] = f2b(y[(long)(b * 128 + c) * 50176 + thw0 + tok]);
    }
    __syncthreads();
    if (tid < 64) {
        float s = 0.f, s2 = 0.f;
        for (int c = 0; c < 128; ++c) { float v = b2f(sRes[tid][c]); s += v; s2 += v * v; }
        float mu = s * (1.0f / 128.0f);
        float var = s2 * (1.0f / 128.0f) - mu * mu;
        sMu[tid] = mu; sRstd[tid] = rsqrtf(fmaxf(var, 0.f) + 1e-5f);
    }
    __syncthreads();
    for (int idx = tid; idx < 64 * 128; idx += 256) {
        int tok = idx >> 7; int c = idx & 127;
        float v = (b2f(sRes[tok][c]) - sMu[tok]) * sRstd[tok] * sG[c] + sBt[c];
        sLN[tok][c] = f2b(v);
    }

    int w = tid >> 6, lane = tid & 63;
    int quad = lane >> 4, l16 = lane & 15;
    int w16 = w * 16;
    f32x4 facc[8];
    #pragma unroll
    for (int t = 0; t < 8; ++t) facc[t] = (f32x4){0.f, 0.f, 0.f, 0.f};

    for (int ch = 0; ch < 16; ++ch) {
        __syncthreads();   // prev fc2 readers of sW2t done; also covers sLN writes on ch==0
        // W1 chunk transposed: sW1t[j][c] = w1[c*512 + ch*32 + j]  (coalesced over j)
        for (int idx = tid; idx < 32 * 128; idx += 256) {
            int c = idx >> 5; int j = idx & 31;
            sW1t[j][c] = f2b(w1[c * 512 + ch * 32 + j]);
        }
        // W2 chunk transposed: sW2t[c][j] = w2[(ch*32+j)*128 + c]  (coalesced over c)
        for (int idx = tid; idx < 32 * 128; idx += 256) {
            int j = idx >> 7; int c = idx & 127;
            sW2t[c][j] = f2b(w2[(ch * 32 + j) * 128 + c]);
        }
        __syncthreads();
        // fc1: A = sLN rows [w16..w16+15], B = sW1t; 2 N-tiles of 16
        #pragma unroll
        for (int t = 0; t < 2; ++t) {
            f32x4 a = (f32x4){0.f, 0.f, 0.f, 0.f};
            #pragma unroll
            for (int kk = 0; kk < 4; ++kk) {
                short8 af = *(const short8*)&sLN[w16 + l16][kk * 32 + quad * 8];
                short8 bf = *(const short8*)&sW1t[t * 16 + l16][kk * 32 + quad * 8];
                a = __builtin_amdgcn_mfma_f32_16x16x32_bf16(af, bf, a, 0, 0, 0);
            }
            float bias = b1[ch * 32 + t * 16 + l16];
            #pragma unroll
            for (int r = 0; r < 4; ++r) {
                float v = a[r] + bias;
                v = 0.5f * v * (1.0f + erff(v * 0.70710678118f));
                sH[w16 + quad * 4 + r][t * 16 + l16] = f2b(v);
            }
        }
        __syncthreads();   // sH producers -> consumers (cross-quad within wave is NOT enough: fc2 A-frag reads all 16 rows)
        // fc2: A = sH rows [w16..], K=32; B = sW2t; 8 N-tiles over 128 channels
        short8 hf = *(const short8*)&sH[w16 + l16][quad * 8];
        #pragma unroll
        for (int t = 0; t < 8; ++t) {
            short8 wf = *(const short8*)&sW2t[t * 16 + l16][quad * 8];
            facc[t] = __builtin_amdgcn_mfma_f32_16x16x32_bf16(hf, wf, facc[t], 0, 0, 0);
        }
    }
    // epilogue: bias + residual, stage transposed via sLN region (each wave touches only its own 16 rows)
    bf16 (*sOut)[136] = sLN;
    #pragma unroll
    for (int t = 0; t < 8; ++t) {
        int c = t * 16 + l16;
        float b2v = b2[c];
        #pragma unroll
        for (int r = 0; r < 4; ++r) {
            int m = w16 + quad * 4 + r;
            float v = facc[t][r] + b2v + b2f(sRes[m][c]);
            sOut[m][c] = f2b(v);
        }
    }
    __syncthreads();
    for (int idx = tid; idx < 64 * 128; idx += 256) {
        int c = idx >> 6; int tok = idx & 63;
        y[(long)(b * 128 + c) * 50176 + thw0 + tok] = b2f(sOut[tok][c]);
    }
}

// ----------------------------------------------------------------
extern "C" void kernel_launch(void* const* d_in, const int* in_sizes, int n_in,
                              void* d_out, int out_size, void* d_ws, size_t ws_size,
                              hipStream_t stream) {
    const float* x      = (const float*)d_in[0];
    const float* bn_g   = (const float*)d_in[1];
    const float* bn_b   = (const float*)d_in[2];
    const float* bn_m   = (const float*)d_in[3];
    const float* bn_v   = (const float*)d_in[4];
    const float* qkv_w  = (const float*)d_in[5];
    const float* qkv_b  = (const float*)d_in[6];
    const float* proj_w = (const float*)d_in[7];
    const float* proj_b = (const float*)d_in[8];
    const float* ln_g   = (const float*)d_in[9];
    const float* ln_b   = (const float*)d_in[10];
    const float* fc1_w  = (const float*)d_in[11];
    const float* fc1_b  = (const float*)d_in[12];
    const float* fc2_w  = (const float*)d_in[13];
    const float* fc2_b  = (const float*)d_in[14];
    float* out = (float*)d_out;

    // pick batch count so per-batch ws footprint (4 bf16 buffers) fits ws_size
    int NB = 1;
    while (NB < 64 && (size_t)205520896ull / NB > ws_size) NB *= 2;
    int WPB = 1024 / NB;             // windows per batch (>=16 so TPB%64==0)
    int TPB = WPB * 196;             // tokens per batch
    size_t seg = (size_t)TPB * 128 * 2;  // bytes per bf16 buffer

    char* ws = (char*)d_ws;
    bf16* win = (bf16*)(ws);             // reused as attn_out
    bf16* Qb  = (bf16*)(ws + seg);
    bf16* Kb  = (bf16*)(ws + 2 * seg);
    bf16* Vb  = (bf16*)(ws + 3 * seg);

    for (int bi = 0; bi < NB; ++bi) {
        int bw0 = bi * WPB;
        k1_bn_window<<<dim3(WPB), dim3(256), 0, stream>>>(x, bn_g, bn_b, bn_m, bn_v, win, bw0);
        k2_qkv<<<dim3(TPB / 64, 6), dim3(256), 0, stream>>>(win, qkv_w, qkv_b, Qb, Kb, Vb);
        k3_attn<<<dim3(WPB * 4), dim3(256), 0, stream>>>(Qb, Kb, Vb, win);
        k4_proj<<<dim3(TPB / 64, 2), dim3(256), 0, stream>>>(win, proj_w, proj_b, x, out, bw0);
    }
    k5_mlp<<<dim3(3136), dim3(256), 0, stream>>>(out, ln_g, ln_b, fc1_w, fc1_b, fc2_w, fc2_b);
}

// Round 6
// 1718.563 us; speedup vs baseline: 2.9291x; 1.8533x over previous
//
#include <hip/hip_runtime.h>
#include <hip/hip_bf16.h>
#include <math.h>

// LocalUniFormerBlock: BN -> windowed MHSA -> +res -> LN -> MLP(gelu) -> +res
// B=4 C=128 T=16 H=56 W=56, windows 4x7x7 (N=196), NH=4 HD=32, HID=512
//
// Round-6: k3 attention converted to MFMA (16x16x32 bf16), flash-style but
// single-pass softmax without max subtraction (logits sigma ~0.05 — exp is
// perfectly conditioned). P goes C-layout -> LDS -> A-layout per wave.
// k1/k2/k4/k5 byte-identical to the round-5 passing version.

typedef __hip_bfloat16 bf16;
typedef __attribute__((ext_vector_type(8))) short short8;
typedef __attribute__((ext_vector_type(4))) float f32x4;

__device__ __forceinline__ float b2f(bf16 v) { return __bfloat162float(v); }
__device__ __forceinline__ bf16  f2b(float v) { return __float2bfloat16(v); }

// ---------------------------------------------------------------- K1: BN + window partition (batched)
__global__ __launch_bounds__(256) void k1_bn_window(
    const float* __restrict__ x, const float* __restrict__ gamma, const float* __restrict__ beta,
    const float* __restrict__ mean, const float* __restrict__ var, bf16* __restrict__ win, int bw0)
{
    __shared__ bf16 sXn[196][130];
    __shared__ float sAc[128], sBc[128];
    int gbw = bw0 + blockIdx.x;      // global window id
    int b   = gbw >> 8;
    int wid = gbw & 255;
    int t0 = (wid >> 6) * 4;
    int h0 = ((wid >> 3) & 7) * 7;
    int w0 = (wid & 7) * 7;
    int tid = threadIdx.x;
    if (tid < 128) {
        float a = gamma[tid] * rsqrtf(var[tid] + 1e-5f);
        sAc[tid] = a;
        sBc[tid] = beta[tid] - mean[tid] * a;
    }
    __syncthreads();
    for (int idx = tid; idx < 128 * 196; idx += 256) {
        int c = idx / 196;
        int n = idx - c * 196;
        int wt = n / 49; int rem = n - wt * 49;
        int wh = rem / 7; int ww = rem - wh * 7;
        int gi = (((b * 128 + c) * 16 + (t0 + wt)) * 56 + (h0 + wh)) * 56 + (w0 + ww);
        float v = x[gi];
        sXn[n][c] = f2b(v * sAc[c] + sBc[c]);
    }
    __syncthreads();
    bf16* dst = win + (long)blockIdx.x * (196 * 128);   // batch-local row
    for (int idx = tid; idx < 196 * 128; idx += 256) {
        int n = idx >> 7; int c = idx & 127;
        dst[idx] = sXn[n][c];
    }
}

// ---------------------------------------------------------------- K2: QKV GEMM (batch-local M, N=384, K=128)
__global__ __launch_bounds__(256) void k2_qkv(
    const bf16* __restrict__ win, const float* __restrict__ qkv_w, const float* __restrict__ qkv_b,
    bf16* __restrict__ Q, bf16* __restrict__ K, bf16* __restrict__ V)
{
    __shared__ bf16 sA[64][130];
    __shared__ bf16 sB[128][68];
    int t0 = blockIdx.x * 64;        // batch-local token
    int j0 = blockIdx.y * 64;
    int tid = threadIdx.x;
    for (int idx = tid; idx < 64 * 128; idx += 256) {
        int i = idx >> 7; int c = idx & 127;
        sA[i][c] = win[(long)(t0 + i) * 128 + c];
    }
    for (int idx = tid; idx < 128 * 64; idx += 256) {
        int c = idx >> 6; int j = idx & 63;
        sB[c][j] = f2b(qkv_w[c * 384 + j0 + j]);
    }
    __syncthreads();
    int tx = tid & 15, ty = tid >> 4;
    float acc[4][4] = {};
    for (int c = 0; c < 128; ++c) {
        float a0 = b2f(sA[ty * 4 + 0][c]);
        float a1 = b2f(sA[ty * 4 + 1][c]);
        float a2 = b2f(sA[ty * 4 + 2][c]);
        float a3 = b2f(sA[ty * 4 + 3][c]);
        float bb0 = b2f(sB[c][tx * 4 + 0]);
        float bb1 = b2f(sB[c][tx * 4 + 1]);
        float bb2 = b2f(sB[c][tx * 4 + 2]);
        float bb3 = b2f(sB[c][tx * 4 + 3]);
        acc[0][0] += a0 * bb0; acc[0][1] += a0 * bb1; acc[0][2] += a0 * bb2; acc[0][3] += a0 * bb3;
        acc[1][0] += a1 * bb0; acc[1][1] += a1 * bb1; acc[1][2] += a1 * bb2; acc[1][3] += a1 * bb3;
        acc[2][0] += a2 * bb0; acc[2][1] += a2 * bb1; acc[2][2] += a2 * bb2; acc[2][3] += a2 * bb3;
        acc[3][0] += a3 * bb0; acc[3][1] += a3 * bb1; acc[3][2] += a3 * bb2; acc[3][3] += a3 * bb3;
    }
    bf16* outw = (j0 < 128) ? Q : (j0 < 256 ? K : V);
    int jb = j0 & 127;
    for (int di = 0; di < 4; ++di) {
        int tk = t0 + ty * 4 + di;
        int lbw = tk / 196; int n = tk - lbw * 196;  // batch-local window
        for (int dj = 0; dj < 4; ++dj) {
            int j = tx * 4 + dj;
            int hd = jb + j;
            int h = hd >> 5; int d = hd & 31;
            float v = acc[di][dj] + qkv_b[j0 + j];
            outw[((long)(lbw * 4 + h) * 196 + n) * 32 + d] = f2b(v);
        }
    }
}

// ---------------------------------------------------------------- K3: MFMA attention per (batch-local window, head)
// S = Q·K^T via mfma(A=Q[m][k], B=K[n][k]); P=exp(S·scale) (no max-sub; sigma(S)~0.05);
// P C-layout -> per-wave LDS tile -> A-layout; O = P·V via mfma(A=P, B=V^T[n=d][k=j]).
__global__ __launch_bounds__(256) void k3_attn(
    const bf16* __restrict__ Q, const bf16* __restrict__ K, const bf16* __restrict__ V,
    bf16* __restrict__ attn_out)
{
    __shared__ __align__(16) bf16 sQ[208][40];    // [q row][d], rows 196..207 zero
    __shared__ __align__(16) bf16 sK[224][40];    // [k row][d], rows 196..223 zero
    __shared__ __align__(16) bf16 sVt[32][232];   // [d][j], j 196..223 zero
    __shared__ __align__(16) bf16 sP[4][16][40];  // per-wave P chunk [m][k]
    int bh = blockIdx.x;             // batch-local bw*4 + h
    int bw = bh >> 2; int h = bh & 3;
    int tid = threadIdx.x;
    const bf16* qp = Q + (long)bh * 6272;
    const bf16* kp = K + (long)bh * 6272;
    const bf16* vp = V + (long)bh * 6272;
    short8 z8 = {0, 0, 0, 0, 0, 0, 0, 0};
    for (int idx = tid; idx < 784; idx += 256) {      // 196 rows x 32 d, 8-wide
        int row = idx >> 2; int c8 = (idx & 3) * 8;
        *(short8*)&sQ[row][c8] = *(const short8*)&qp[idx * 8];
        *(short8*)&sK[row][c8] = *(const short8*)&kp[idx * 8];
    }
    for (int idx = tid; idx < 48; idx += 256) {       // Q pad rows 196..207
        *(short8*)&sQ[196 + (idx >> 2)][(idx & 3) * 8] = z8;
    }
    for (int idx = tid; idx < 112; idx += 256) {      // K pad rows 196..223
        *(short8*)&sK[196 + (idx >> 2)][(idx & 3) * 8] = z8;
    }
    for (int idx = tid; idx < 6272; idx += 256) {     // V transpose
        int j = idx >> 5; int d = idx & 31;
        sVt[d][j] = vp[idx];
    }
    for (int idx = tid; idx < 32 * 28; idx += 256) {  // V^T pad cols 196..223
        int d = idx / 28; int j = 196 + (idx - d * 28);
        sVt[d][j] = f2b(0.f);
    }
    __syncthreads();
    int w = tid >> 6, lane = tid & 63;
    int quad = lane >> 4, l16 = lane & 15;
    const float scale = 0.17677669529663687f;
    const f32x4 zero4 = {0.f, 0.f, 0.f, 0.f};
    for (int mt = w; mt < 13; mt += 4) {
        short8 qf = *(const short8*)&sQ[mt * 16 + l16][quad * 8];
        f32x4 oacc0 = zero4, oacc1 = zero4;
        float lsum[4] = {0.f, 0.f, 0.f, 0.f};
        for (int cc = 0; cc < 7; ++cc) {
            #pragma unroll
            for (int t2 = 0; t2 < 2; ++t2) {
                int col0 = cc * 32 + t2 * 16;
                short8 kf = *(const short8*)&sK[col0 + l16][quad * 8];
                f32x4 s = __builtin_amdgcn_mfma_f32_16x16x32_bf16(qf, kf, zero4, 0, 0, 0);
                bool valid = (col0 + l16) < 196;
                #pragma unroll
                for (int r = 0; r < 4; ++r) {
                    float p = valid ? __expf(s[r] * scale) : 0.f;
                    lsum[r] += p;
                    sP[w][quad * 4 + r][t2 * 16 + l16] = f2b(p);
                }
            }
            // same-wave LDS write->read (lockstep; pattern HW-validated by old k3)
            short8 pf  = *(const short8*)&sP[w][l16][quad * 8];
            short8 vf0 = *(const short8*)&sVt[l16][cc * 32 + quad * 8];
            short8 vf1 = *(const short8*)&sVt[16 + l16][cc * 32 + quad * 8];
            oacc0 = __builtin_amdgcn_mfma_f32_16x16x32_bf16(pf, vf0, oacc0, 0, 0, 0);
            oacc1 = __builtin_amdgcn_mfma_f32_16x16x32_bf16(pf, vf1, oacc1, 0, 0, 0);
        }
        #pragma unroll
        for (int off = 1; off < 16; off <<= 1) {
            #pragma unroll
            for (int r = 0; r < 4; ++r) lsum[r] += __shfl_xor(lsum[r], off, 64);
        }
        #pragma unroll
        for (int r = 0; r < 4; ++r) {
            int row = mt * 16 + quad * 4 + r;
            if (row < 196) {
                float inv = 1.0f / lsum[r];
                bf16* op = attn_out + ((long)(bw * 196) + row) * 128 + h * 32;
                op[l16]      = f2b(oacc0[r] * inv);
                op[16 + l16] = f2b(oacc1[r] * inv);
            }
        }
    }
}

// ---------------------------------------------------------------- K4: proj GEMM + residual -> d_out (ch-major, fp32)
__global__ __launch_bounds__(256) void k4_proj(
    const bf16* __restrict__ attn, const float* __restrict__ proj_w, const float* __restrict__ proj_b,
    const float* __restrict__ x, float* __restrict__ y, int bw0)
{
    __shared__ bf16 sA[64][130];
    __shared__ bf16 sB[128][68];
    int t0 = blockIdx.x * 64;        // batch-local token
    int j0 = blockIdx.y * 64;
    int tid = threadIdx.x;
    for (int idx = tid; idx < 64 * 128; idx += 256) {
        int i = idx >> 7; int c = idx & 127;
        sA[i][c] = attn[(long)(t0 + i) * 128 + c];
    }
    for (int idx = tid; idx < 128 * 64; idx += 256) {
        int c = idx >> 6; int j = idx & 63;
        sB[c][j] = f2b(proj_w[c * 128 + j0 + j]);
    }
    __syncthreads();
    int tx = tid & 15, ty = tid >> 4;
    float acc[4][4] = {};
    for (int c = 0; c < 128; ++c) {
        float a0 = b2f(sA[ty * 4 + 0][c]);
        float a1 = b2f(sA[ty * 4 + 1][c]);
        float a2 = b2f(sA[ty * 4 + 2][c]);
        float a3 = b2f(sA[ty * 4 + 3][c]);
        float bb0 = b2f(sB[c][tx * 4 + 0]);
        float bb1 = b2f(sB[c][tx * 4 + 1]);
        float bb2 = b2f(sB[c][tx * 4 + 2]);
        float bb3 = b2f(sB[c][tx * 4 + 3]);
        acc[0][0] += a0 * bb0; acc[0][1] += a0 * bb1; acc[0][2] += a0 * bb2; acc[0][3] += a0 * bb3;
        acc[1][0] += a1 * bb0; acc[1][1] += a1 * bb1; acc[1][2] += a1 * bb2; acc[1][3] += a1 * bb3;
        acc[2][0] += a2 * bb0; acc[2][1] += a2 * bb1; acc[2][2] += a2 * bb2; acc[2][3] += a2 * bb3;
        acc[3][0] += a3 * bb0; acc[3][1] += a3 * bb1; acc[3][2] += a3 * bb2; acc[3][3] += a3 * bb3;
    }
    for (int di = 0; di < 4; ++di) {
        int tk = t0 + ty * 4 + di;
        int gbw = bw0 + tk / 196;    // global window id
        int n = tk - (tk / 196) * 196;
        int b = gbw >> 8; int wid = gbw & 255;
        int wt = n / 49; int rem = n - wt * 49;
        int t = (wid >> 6) * 4 + wt;
        int hh = ((wid >> 3) & 7) * 7 + rem / 7;
        int wcol = (wid & 7) * 7 + (rem - (rem / 7) * 7);
        int thw = (t * 56 + hh) * 56 + wcol;
        for (int dj = 0; dj < 4; ++dj) {
            int j = j0 + tx * 4 + dj;
            float v = acc[di][dj] + proj_b[j] + x[(long)(b * 128 + j) * 50176 + thw];
            y[(long)(b * 128 + j) * 50176 + thw] = v;    // channel-major fp32, same layout as out
        }
    }
}

// ---------------------------------------------------------------- K5: LN + MLP (MFMA) + residual, IN-PLACE on d_out
__global__ __launch_bounds__(256) void k5_mlp(
    float* __restrict__ y,           // in: x+attn residual (ch-major); out: final (ch-major)
    const float* __restrict__ ln_g, const float* __restrict__ ln_b,
    const float* __restrict__ w1, const float* __restrict__ b1,
    const float* __restrict__ w2, const float* __restrict__ b2)
{
    __shared__ __align__(16) bf16 sLN[64][136];   // LN activations; reused as out-stage
    __shared__ __align__(16) bf16 sW1t[32][136];  // W1 chunk, [hidden j][c]
    __shared__ __align__(16) bf16 sH[64][40];     // gelu(fc1) chunk, [tok][j]
    __shared__ __align__(16) bf16 sW2t[128][40];  // W2 chunk, [c][hidden j]
    __shared__ bf16 sRes[64][129];
    __shared__ float sMu[64], sRstd[64];
    __shared__ float sG[128], sBt[128];
    int tid = threadIdx.x;
    int g0 = blockIdx.x * 64;        // 50176%64==0 so one b per block
    int b = g0 / 50176;
    int thw0 = g0 - b * 50176;
    if (tid < 128) { sG[tid] = ln_g[tid]; sBt[tid] = ln_b[tid]; }
    for (int idx = tid; idx < 64 * 128; idx += 256) {
        int c = idx >> 6; int tok = idx & 63;
        sRes[tok][c] = f2b(y[(long)(b * 128 + c) * 50176 + thw0 + tok]);
    }
    __syncthreads();
    if (tid < 64) {
        float s = 0.f, s2 = 0.f;
        for (int c = 0; c < 128; ++c) { float v = b2f(sRes[tid][c]); s += v; s2 += v * v; }
        float mu = s * (1.0f / 128.0f);
        float var = s2 * (1.0f / 128.0f) - mu * mu;
        sMu[tid] = mu; sRstd[tid] = rsqrtf(fmaxf(var, 0.f) + 1e-5f);
    }
    __syncthreads();
    for (int idx = tid; idx < 64 * 128; idx += 256) {
        int tok = idx >> 7; int c = idx & 127;
        float v = (b2f(sRes[tok][c]) - sMu[tok]) * sRstd[tok] * sG[c] + sBt[c];
        sLN[tok][c] = f2b(v);
    }

    int w = tid >> 6, lane = tid & 63;
    int quad = lane >> 4, l16 = lane & 15;
    int w16 = w * 16;
    f32x4 facc[8];
    #pragma unroll
    for (int t = 0; t < 8; ++t) facc[t] = (f32x4){0.f, 0.f, 0.f, 0.f};

    for (int ch = 0; ch < 16; ++ch) {
        __syncthreads();   // prev fc2 readers of sW2t done; also covers sLN writes on ch==0
        for (int idx = tid; idx < 32 * 128; idx += 256) {
            int c = idx >> 5; int j = idx & 31;
            sW1t[j][c] = f2b(w1[c * 512 + ch * 32 + j]);
        }
        for (int idx = tid; idx < 32 * 128; idx += 256) {
            int j = idx >> 7; int c = idx & 127;
            sW2t[c][j] = f2b(w2[(ch * 32 + j) * 128 + c]);
        }
        __syncthreads();
        #pragma unroll
        for (int t = 0; t < 2; ++t) {
            f32x4 a = (f32x4){0.f, 0.f, 0.f, 0.f};
            #pragma unroll
            for (int kk = 0; kk < 4; ++kk) {
                short8 af = *(const short8*)&sLN[w16 + l16][kk * 32 + quad * 8];
                short8 bf = *(const short8*)&sW1t[t * 16 + l16][kk * 32 + quad * 8];
                a = __builtin_amdgcn_mfma_f32_16x16x32_bf16(af, bf, a, 0, 0, 0);
            }
            float bias = b1[ch * 32 + t * 16 + l16];
            #pragma unroll
            for (int r = 0; r < 4; ++r) {
                float v = a[r] + bias;
                v = 0.5f * v * (1.0f + erff(v * 0.70710678118f));
                sH[w16 + quad * 4 + r][t * 16 + l16] = f2b(v);
            }
        }
        __syncthreads();   // sH producers -> consumers across waves' quads
        short8 hf = *(const short8*)&sH[w16 + l16][quad * 8];
        #pragma unroll
        for (int t = 0; t < 8; ++t) {
            short8 wf = *(const short8*)&sW2t[t * 16 + l16][quad * 8];
            facc[t] = __builtin_amdgcn_mfma_f32_16x16x32_bf16(hf, wf, facc[t], 0, 0, 0);
        }
    }
    bf16 (*sOut)[136] = sLN;
    #pragma unroll
    for (int t = 0; t < 8; ++t) {
        int c = t * 16 + l16;
        float b2v = b2[c];
        #pragma unroll
        for (int r = 0; r < 4; ++r) {
            int m = w16 + quad * 4 + r;
            float v = facc[t][r] + b2v + b2f(sRes[m][c]);
            sOut[m][c] = f2b(v);
        }
    }
    __syncthreads();
    for (int idx = tid; idx < 64 * 128; idx += 256) {
        int c = idx >> 6; int tok = idx & 63;
        y[(long)(b * 128 + c) * 50176 + thw0 + tok] = b2f(sOut[tok][c]);
    }
}

// ----------------------------------------------------------------
extern "C" void kernel_launch(void* const* d_in, const int* in_sizes, int n_in,
                              void* d_out, int out_size, void* d_ws, size_t ws_size,
                              hipStream_t stream) {
    const float* x      = (const float*)d_in[0];
    const float* bn_g   = (const float*)d_in[1];
    const float* bn_b   = (const float*)d_in[2];
    const float* bn_m   = (const float*)d_in[3];
    const float* bn_v   = (const float*)d_in[4];
    const float* qkv_w  = (const float*)d_in[5];
    const float* qkv_b  = (const float*)d_in[6];
    const float* proj_w = (const float*)d_in[7];
    const float* proj_b = (const float*)d_in[8];
    const float* ln_g   = (const float*)d_in[9];
    const float* ln_b   = (const float*)d_in[10];
    const float* fc1_w  = (const float*)d_in[11];
    const float* fc1_b  = (const float*)d_in[12];
    const float* fc2_w  = (const float*)d_in[13];
    const float* fc2_b  = (const float*)d_in[14];
    float* out = (float*)d_out;

    // pick batch count so per-batch ws footprint (4 bf16 buffers) fits ws_size
    int NB = 1;
    while (NB < 64 && (size_t)205520896ull / NB > ws_size) NB *= 2;
    int WPB = 1024 / NB;             // windows per batch (>=16 so TPB%64==0)
    int TPB = WPB * 196;             // tokens per batch
    size_t seg = (size_t)TPB * 128 * 2;  // bytes per bf16 buffer

    char* ws = (char*)d_ws;
    bf16* win = (bf16*)(ws);             // reused as attn_out
    bf16* Qb  = (bf16*)(ws + seg);
    bf16* Kb  = (bf16*)(ws + 2 * seg);
    bf16* Vb  = (bf16*)(ws + 3 * seg);

    for (int bi = 0; bi < NB; ++bi) {
        int bw0 = bi * WPB;
        k1_bn_window<<<dim3(WPB), dim3(256), 0, stream>>>(x, bn_g, bn_b, bn_m, bn_v, win, bw0);
        k2_qkv<<<dim3(TPB / 64, 6), dim3(256), 0, stream>>>(win, qkv_w, qkv_b, Qb, Kb, Vb);
        k3_attn<<<dim3(WPB * 4), dim3(256), 0, stream>>>(Qb, Kb, Vb, win);
        k4_proj<<<dim3(TPB / 64, 2), dim3(256), 0, stream>>>(win, proj_w, proj_b, x, out, bw0);
    }
    k5_mlp<<<dim3(3136), dim3(256), 0, stream>>>(out, ln_g, ln_b, fc1_w, fc1_b, fc2_w, fc2_b);
}